// Round 5
// baseline (678.447 us; speedup 1.0000x reference)
//
#include <hip/hip_runtime.h>
#include <hip/hip_bf16.h>

#define B_ 4
#define Q_ 1024
#define MEM_ 1024
#define D_ 1024
#define H_ 16
#define DH_ 64
#define KLEN_ 2048
#define NSPLIT 2

typedef __hip_bfloat16 bf16;
typedef __bf16 bf16x8 __attribute__((ext_vector_type(8)));
typedef float f32x4 __attribute__((ext_vector_type(4)));

__device__ __forceinline__ float bf2f(bf16 x) { return __bfloat162float(x); }
__device__ __forceinline__ bf16 f2bf(float x) { return __float2bfloat16(x); }

__device__ __forceinline__ unsigned short f2bf_bits(float x) {
  union { float f; unsigned u; } a; a.f = x;
  unsigned u = a.u;
  unsigned r = u + 0x7FFFu + ((u >> 16) & 1u);
  return (unsigned short)(r >> 16);
}

#define MFMA16(a, b, c) __builtin_amdgcn_mfma_f32_16x16x32_bf16((a), (b), (c), 0, 0, 0)
#define GLDS(gsrc, ldst) __builtin_amdgcn_global_load_lds( \
    (const __attribute__((address_space(1))) void*)(gsrc), \
    (__attribute__((address_space(3))) void*)(ldst), 16, 0, 0)

// ---------------- conversions ----------------
struct CvtArgs { const float* src[3]; bf16* dst[3]; int n4[3]; };

__global__ void cvt_kernel(CvtArgs a) {
  const int z = blockIdx.z;
  const float4* s = (const float4*)a.src[z];
  const int n4 = a.n4[z];
  const int i = blockIdx.x * blockDim.x + threadIdx.x;
  if (i < n4) {
    float4 v = s[i];
    ushort4 o;
    o.x = f2bf_bits(v.x); o.y = f2bf_bits(v.y);
    o.z = f2bf_bits(v.z); o.w = f2bf_bits(v.w);
    ((ushort4*)a.dst[z])[i] = o;
  }
}

// ---------------- weight transpose (f32 -> bf16, Wt[n][k] = W[k][n]) -------
struct TpArgs { const float* w[5]; bf16* o[5]; };

__global__ void tp_kernel(TpArgs a) {
  __shared__ float t[32][33];
  const int z = blockIdx.z;
  const float* W = a.w[z];
  bf16* Wt = a.o[z];
  const int bx = blockIdx.x * 32, by = blockIdx.y * 32;
  const int tx = threadIdx.x, ty = threadIdx.y;
#pragma unroll
  for (int y = ty; y < 32; y += 8) t[y][tx] = W[(long)(by + y) * D_ + bx + tx];
  __syncthreads();
#pragma unroll
  for (int y = ty; y < 32; y += 8)
    Wt[(long)(bx + y) * D_ + by + tx] = f2bf(t[tx][y]);
}

// ---------------- GEMM (A row-major MxK bf16, Bt row-major NxK bf16) -------
enum { EPI_HQKV = 0, EPI_MEMKV, EPI_R, EPI_OUT };

struct GemmArgs {
  const bf16* A; const bf16* Bt;
  int K;
  long batchA, batchB;
  bf16 *qw, *qr, *kall, *vT, *rhead;
  float *kcache, *vcache, *fout;
  const float *rwb, *rrb;
};

template <int MODE>
__global__ __launch_bounds__(256) void gemm_bt(GemmArgs g) {
  __shared__ bf16 As[128 * 32];
  __shared__ bf16 Bs[128 * 32];
  const int tid = threadIdx.x;
  const int wid = tid >> 6, lane = tid & 63;
  const int wr = wid >> 1, wc = wid & 1;
  const int lo = lane & 15, lg = lane >> 4;
  const int m0 = blockIdx.y * 128, n0 = blockIdx.x * 128;
  const int K = g.K;
  const bf16* A = g.A + (long)blockIdx.z * g.batchA;
  const bf16* Bt = g.Bt + (long)blockIdx.z * g.batchB;

  f32x4 acc[4][4] = {};

  const int srow = 32 * wid + (lane >> 2);
  const int scol = (lane & 3) * 8;
  const bf16* asrc = A + (long)(m0 + srow) * K + scol;
  const bf16* bsrc = Bt + (long)(n0 + srow) * K + scol;
  bf16* adst0 = &As[(32 * wid) * 32];
  bf16* adst1 = &As[(32 * wid + 16) * 32];
  bf16* bdst0 = &Bs[(32 * wid) * 32];
  bf16* bdst1 = &Bs[(32 * wid + 16) * 32];

  for (int kt = 0; kt < K; kt += 32) {
    GLDS(asrc, adst0);
    GLDS(asrc + 16 * (long)K, adst1);
    GLDS(bsrc, bdst0);
    GLDS(bsrc + 16 * (long)K, bdst1);
    asrc += 32; bsrc += 32;
    __syncthreads();
    bf16x8 af[4], bfv[4];
#pragma unroll
    for (int m = 0; m < 4; ++m)
      af[m] = *(const bf16x8*)&As[(64 * wr + 16 * m + lo) * 32 + lg * 8];
#pragma unroll
    for (int n = 0; n < 4; ++n)
      bfv[n] = *(const bf16x8*)&Bs[(64 * wc + 16 * n + lo) * 32 + lg * 8];
#pragma unroll
    for (int m = 0; m < 4; ++m)
#pragma unroll
      for (int n = 0; n < 4; ++n)
        acc[m][n] = MFMA16(af[m], bfv[n], acc[m][n]);
    __syncthreads();
  }

#pragma unroll
  for (int m = 0; m < 4; ++m) {
#pragma unroll
    for (int n = 0; n < 4; ++n) {
#pragma unroll
      for (int r = 0; r < 4; ++r) {
        const float v = acc[m][n][r];
        const int gr = m0 + 64 * wr + 16 * m + lg * 4 + r;
        const int gc = n0 + 64 * wc + 16 * n + lo;
        if constexpr (MODE == EPI_HQKV) {
          const int b = gr >> 10, i = gr & 1023;
          const int seg = gc >> 10, c = gc & 1023;
          const int hh = c >> 6, dh = c & 63;
          const long bh = (long)(b * H_ + hh);
          if (seg == 0) {
            // fold 1/sqrt(DH)=0.125 into q so attn skips the per-score scale
            const long idx = (bh * Q_ + i) * DH_ + dh;
            g.qw[idx] = f2bf((v + g.rwb[c]) * 0.125f);
            g.qr[idx] = f2bf((v + g.rrb[c]) * 0.125f);
          } else if (seg == 1) {
            g.kall[(bh * KLEN_ + MEM_ + i) * DH_ + dh] = f2bf(v);
            g.kcache[(bh * MEM_ + i) * DH_ + dh] = v;
          } else {
            g.vT[(bh * DH_ + dh) * KLEN_ + MEM_ + i] = f2bf(v);
            g.vcache[(bh * MEM_ + i) * DH_ + dh] = v;
          }
        } else if constexpr (MODE == EPI_MEMKV) {
          const int b = gr >> 10, i = gr & 1023;
          const int seg = gc >> 10, c = gc & 1023;
          const int hh = c >> 6, dh = c & 63;
          const long bh = (long)(b * H_ + hh);
          if (seg == 0) g.kall[(bh * KLEN_ + i) * DH_ + dh] = f2bf(v);
          else          g.vT[(bh * DH_ + dh) * KLEN_ + i] = f2bf(v);
        } else if constexpr (MODE == EPI_R) {
          const int hh = gc >> 6, dh = gc & 63;
          g.rhead[((long)hh * KLEN_ + gr) * DH_ + dh] = f2bf(v);
        } else {  // EPI_OUT
          g.fout[(long)gr * D_ + gc] = v;
        }
      }
    }
  }
}

// ---------------- fused attention, KV-split + XCD swizzle ------------------
// 1D grid of 2048 hw blocks. Logical L = ((hw&7)<<8) | (hw>>3) groups the 16
// x-blocks of one (b,h,js) on one XCD (K/V-half stays L2-resident).
// __launch_bounds__(256,4): cap total regs/wave at 128 -> 4 blocks/CU
// (R4 evidence: residency stuck at ~2.4 blocks/CU == unified-file reg cap).
__global__ __launch_bounds__(256, 4) void attn_kernel(
    const bf16* __restrict__ qw, const bf16* __restrict__ qr,
    const bf16* __restrict__ kall, const bf16* __restrict__ vT,
    const bf16* __restrict__ rhead, float* __restrict__ po,
    float2* __restrict__ pml) {
  __shared__ bf16 Ps[4][16][72];
  __shared__ bf16 Sd[4][16][83];
  const int hw = blockIdx.x;
  const int L = ((hw & 7) << 8) | (hw >> 3);
  const int xb = L & 15;
  const int h = (L >> 4) & 15;
  const int js = (L >> 8) & 1;
  const int b = L >> 9;
  const int tid = threadIdx.x;
  const int wid = tid >> 6, lane = tid & 63;
  const int lo = lane & 15, lg = lane >> 4;
  const int i0 = xb * 64 + wid * 16;
  const long bh = (long)(b * H_ + h);
  const bf16* rh = rhead + (long)h * KLEN_ * DH_;

  const bf16x8 aq0 = *(const bf16x8*)&qw[(bh * Q_ + i0 + lo) * DH_ + lg * 8];
  const bf16x8 aq1 = *(const bf16x8*)&qw[(bh * Q_ + i0 + lo) * DH_ + 32 + lg * 8];
  const bf16x8 ar0 = *(const bf16x8*)&qr[(bh * Q_ + i0 + lo) * DH_ + lg * 8];
  const bf16x8 ar1 = *(const bf16x8*)&qr[(bh * Q_ + i0 + lo) * DH_ + 32 + lg * 8];

  f32x4 o[4] = {};
  float mrun[4], lrun[4];
#pragma unroll
  for (int r = 0; r < 4; ++r) { mrun[r] = -1e30f; lrun[r] = 0.f; }

  const int jbeg = js << 10, jend = jbeg + (KLEN_ / NSPLIT);
  for (int j0 = jbeg; j0 < jend; j0 += 64) {
    // ---- ac = qw . K^T ----
    f32x4 s[4];
#pragma unroll
    for (int t = 0; t < 4; ++t) {
      const bf16* kp = &kall[(bh * KLEN_ + j0 + 16 * t + lo) * DH_ + lg * 8];
      const bf16x8 kb0 = *(const bf16x8*)kp;
      const bf16x8 kb1 = *(const bf16x8*)(kp + 32);
      f32x4 z = {};
      z = MFMA16(aq0, kb0, z);
      z = MFMA16(aq1, kb1, z);
      s[t] = z;
    }
    // ---- bd band in delta-space: c in [0,80), delta = dbase + c ----
    const int dbase = j0 - i0 - 15;
#pragma unroll
    for (int t = 0; t < 5; ++t) {
      const int dmin = dbase + 16 * t;
      const bool need1 = (dmin <= 1024);
      const bool need2 = (dmin + 15 >= 1026);
      const int dcol = dmin + lo;
      int m = dcol + 1023 - ((dcol >= 1026) ? 2049 : 0);
      m = max(0, min(m, KLEN_ - 1));
      const bf16* rp = &rh[(long)m * DH_ + lg * 8];
      const bf16x8 rb0 = *(const bf16x8*)rp;
      const bf16x8 rb1 = *(const bf16x8*)(rp + 32);
      f32x4 z1 = {}, z2 = {};
      if (need1) { z1 = MFMA16(ar0, rb0, z1); z1 = MFMA16(ar1, rb1, z1); }
      if (need2) {
        // rare branch: load the +1-shifted qr rows here so they are not
        // part of the loop-carried live set (register diet for occupancy)
        const int rs = min(i0 + 1 + lo, Q_ - 1);
        const bf16x8 as0 = *(const bf16x8*)&qr[(bh * Q_ + rs) * DH_ + lg * 8];
        const bf16x8 as1 = *(const bf16x8*)&qr[(bh * Q_ + rs) * DH_ + 32 + lg * 8];
        z2 = MFMA16(as0, rb0, z2);
        z2 = MFMA16(as1, rb1, z2);
      }
#pragma unroll
      for (int r = 0; r < 4; ++r) {
        float v = (dcol >= 1026) ? z2[r] : z1[r];
        if (dcol == 1025) v = 0.f;
        Sd[wid][lg * 4 + r][16 * t + lo] = f2bf(v);
      }
    }
    // ---- softmax (online); q was pre-scaled by 0.125 ----
    float mnew[4];
#pragma unroll
    for (int r = 0; r < 4; ++r) {
      const int row = lg * 4 + r;
      float mt = -1e30f;
#pragma unroll
      for (int t = 0; t < 4; ++t) {
        const float bd = bf2f(Sd[wid][row][16 * t + lo + 15 - row]);
        const float sc = s[t][r] + bd;
        s[t][r] = sc;
        mt = fmaxf(mt, sc);
      }
#pragma unroll
      for (int d = 1; d < 16; d <<= 1) mt = fmaxf(mt, __shfl_xor(mt, d));
      mnew[r] = fmaxf(mrun[r], mt);
    }
#pragma unroll
    for (int r = 0; r < 4; ++r) {
      float rsum = 0.f;
#pragma unroll
      for (int t = 0; t < 4; ++t) {
        const float p = __expf(s[t][r] - mnew[r]);
        s[t][r] = p;
        rsum += p;
      }
#pragma unroll
      for (int d = 1; d < 16; d <<= 1) rsum += __shfl_xor(rsum, d);
      const float scale = __expf(mrun[r] - mnew[r]);
      lrun[r] = lrun[r] * scale + rsum;
      mrun[r] = mnew[r];
#pragma unroll
      for (int u = 0; u < 4; ++u) o[u][r] *= scale;
    }
    // ---- P -> LDS -> A-frag, PV ----
#pragma unroll
    for (int t = 0; t < 4; ++t)
#pragma unroll
      for (int r = 0; r < 4; ++r)
        Ps[wid][lg * 4 + r][16 * t + lo] = f2bf(s[t][r]);
    const bf16x8 pa0 = *(const bf16x8*)&Ps[wid][lo][lg * 8];
    const bf16x8 pa1 = *(const bf16x8*)&Ps[wid][lo][32 + lg * 8];
#pragma unroll
    for (int u = 0; u < 4; ++u) {
      const bf16* vp = &vT[(bh * DH_ + 16 * u + lo) * KLEN_ + j0 + lg * 8];
      const bf16x8 vb0 = *(const bf16x8*)vp;
      const bf16x8 vb1 = *(const bf16x8*)(vp + 32);
      o[u] = MFMA16(pa0, vb0, o[u]);
      o[u] = MFMA16(pa1, vb1, o[u]);
    }
  }
  // ---- partial outputs ----
#pragma unroll
  for (int u = 0; u < 4; ++u) {
#pragma unroll
    for (int r = 0; r < 4; ++r) {
      const int i = i0 + lg * 4 + r;
      po[(((long)(bh * Q_ + i)) * NSPLIT + js) * DH_ + 16 * u + lo] = o[u][r];
    }
  }
  if (lo == 0) {
#pragma unroll
    for (int r = 0; r < 4; ++r) {
      const int i = i0 + lg * 4 + r;
      pml[((long)(bh * Q_ + i)) * NSPLIT + js] = make_float2(mrun[r], lrun[r]);
    }
  }
}

// ---------------- combine partial softmax halves ---------------------------
__global__ __launch_bounds__(256) void combine_kernel(
    const float* __restrict__ po, const float2* __restrict__ pml,
    bf16* __restrict__ attnv) {
  const long gid = (long)blockIdx.x * 256 + threadIdx.x;  // B*H*Q*DH
  const int col = gid & 63;
  const long row = gid >> 6;  // bh*Q + i
  const float2 ml0 = pml[row * NSPLIT];
  const float2 ml1 = pml[row * NSPLIT + 1];
  const float m = fmaxf(ml0.x, ml1.x);
  const float w0 = __expf(ml0.x - m), w1 = __expf(ml1.x - m);
  const float num = po[(row * NSPLIT) * DH_ + col] * w0 +
                    po[(row * NSPLIT + 1) * DH_ + col] * w1;
  const float den = ml0.y * w0 + ml1.y * w1;
  const int b = (int)(row >> 14);
  const int h = (int)(row >> 10) & 15;
  const int i = (int)row & 1023;
  attnv[((long)(b * Q_ + i)) * D_ + h * DH_ + col] = f2bf(num / den);
}

// ---------------- host ----------------
extern "C" void kernel_launch(void* const* d_in, const int* in_sizes, int n_in,
                              void* d_out, int out_size, void* d_ws, size_t ws_size,
                              hipStream_t stream) {
  (void)in_sizes; (void)n_in; (void)out_size; (void)ws_size;
  const float* h_in  = (const float*)d_in[0];
  const float* mem_in= (const float*)d_in[1];
  const float* r_in  = (const float*)d_in[2];
  const float* Wq = (const float*)d_in[3];
  const float* Wk = (const float*)d_in[4];
  const float* Wv = (const float*)d_in[5];
  const float* Wr = (const float*)d_in[6];
  const float* Wo = (const float*)d_in[7];
  const float* rwb = (const float*)d_in[8];
  const float* rrb = (const float*)d_in[9];

  float* out = (float*)d_out;
  float* kcache = out + (long)B_ * Q_ * D_;
  float* vcache = kcache + (long)B_ * H_ * MEM_ * DH_;

  char* w = (char*)d_ws;
  auto alloc = [&](size_t bytes) {
    char* p = w;
    w += (bytes + 255) & ~(size_t)255;
    return p;
  };
  bf16* h_bf   = (bf16*)alloc((size_t)B_ * Q_ * D_ * 2);
  bf16* mem_bf = (bf16*)alloc((size_t)B_ * MEM_ * D_ * 2);
  bf16* r_bf   = (bf16*)alloc((size_t)KLEN_ * D_ * 2);
  bf16* Wqt = (bf16*)alloc((size_t)D_ * D_ * 2);
  bf16* Wkt = (bf16*)alloc((size_t)D_ * D_ * 2);
  bf16* Wvt = (bf16*)alloc((size_t)D_ * D_ * 2);
  bf16* Wrt = (bf16*)alloc((size_t)D_ * D_ * 2);
  bf16* Wot = (bf16*)alloc((size_t)D_ * D_ * 2);
  bf16* qw    = (bf16*)alloc((size_t)B_ * H_ * Q_ * DH_ * 2);
  bf16* qr    = (bf16*)alloc((size_t)B_ * H_ * Q_ * DH_ * 2);
  bf16* kall  = (bf16*)alloc((size_t)B_ * H_ * KLEN_ * DH_ * 2);
  bf16* vT    = (bf16*)alloc((size_t)B_ * H_ * KLEN_ * DH_ * 2);
  bf16* rhead = (bf16*)alloc((size_t)H_ * KLEN_ * DH_ * 2);
  bf16* attnv = (bf16*)alloc((size_t)B_ * Q_ * D_ * 2);
  float* po   = (float*)alloc((size_t)B_ * H_ * Q_ * NSPLIT * DH_ * 4);
  float2* pml = (float2*)alloc((size_t)B_ * H_ * Q_ * NSPLIT * 8);

  // 1. f32 -> bf16 conversions
  CvtArgs ca;
  ca.src[0] = h_in;   ca.dst[0] = h_bf;   ca.n4[0] = B_ * Q_ * D_ / 4;
  ca.src[1] = mem_in; ca.dst[1] = mem_bf; ca.n4[1] = B_ * MEM_ * D_ / 4;
  ca.src[2] = r_in;   ca.dst[2] = r_bf;   ca.n4[2] = KLEN_ * D_ / 4;
  cvt_kernel<<<dim3((B_ * Q_ * D_ / 4 + 255) / 256, 1, 3), 256, 0, stream>>>(ca);

  // 2. weight transposes
  TpArgs ta;
  ta.w[0] = Wq; ta.o[0] = Wqt;
  ta.w[1] = Wk; ta.o[1] = Wkt;
  ta.w[2] = Wv; ta.o[2] = Wvt;
  ta.w[3] = Wr; ta.o[3] = Wrt;
  ta.w[4] = Wo; ta.o[4] = Wot;
  tp_kernel<<<dim3(32, 32, 5), dim3(32, 8), 0, stream>>>(ta);

  GemmArgs g{};
  g.qw = qw; g.qr = qr; g.kall = kall; g.vT = vT; g.rhead = rhead;
  g.kcache = kcache; g.vcache = vcache; g.fout = out; g.rwb = rwb; g.rrb = rrb;

  // 3. h @ [Wq|Wk|Wv]  (M=4096, N=3072, K=1024)
  g.A = h_bf; g.Bt = Wqt; g.K = D_; g.batchA = 0; g.batchB = 0;
  gemm_bt<EPI_HQKV><<<dim3(3 * D_ / 128, B_ * Q_ / 128, 1), 256, 0, stream>>>(g);

  // 4. mem @ [Wk|Wv]  (M=4096, N=2048, K=1024)
  g.A = mem_bf; g.Bt = Wkt;
  gemm_bt<EPI_MEMKV><<<dim3(2 * D_ / 128, B_ * MEM_ / 128, 1), 256, 0, stream>>>(g);

  // 5. r @ Wr  (M=2048, N=1024, K=1024)
  g.A = r_bf; g.Bt = Wrt;
  gemm_bt<EPI_R><<<dim3(D_ / 128, KLEN_ / 128, 1), 256, 0, stream>>>(g);

  // 6. fused attention (KV-split, XCD-swizzled) + combine
  attn_kernel<<<dim3(Q_ / 64 * H_ * B_ * NSPLIT), 256, 0, stream>>>(
      qw, qr, kall, vT, rhead, po, pml);
  combine_kernel<<<dim3(B_ * H_ * Q_ * DH_ / 256), 256, 0, stream>>>(po, pml, attnv);

  // 7. out = attnv @ Wo  (M=4096, N=1024, K=1024)
  g.A = attnv; g.Bt = Wot; g.K = D_; g.batchA = 0; g.batchB = 0;
  gemm_bt<EPI_OUT><<<dim3(D_ / 128, B_ * Q_ / 128, 1), 256, 0, stream>>>(g);
}

// Round 6
// 399.188 us; speedup vs baseline: 1.6996x; 1.6996x over previous
//
#include <hip/hip_runtime.h>
#include <hip/hip_bf16.h>

#define B_ 4
#define Q_ 1024
#define MEM_ 1024
#define D_ 1024
#define H_ 16
#define DH_ 64
#define KLEN_ 2048
#define NSPLIT 2

typedef __hip_bfloat16 bf16;
typedef __bf16 bf16x8 __attribute__((ext_vector_type(8)));
typedef float f32x4 __attribute__((ext_vector_type(4)));

__device__ __forceinline__ float bf2f(bf16 x) { return __bfloat162float(x); }
__device__ __forceinline__ bf16 f2bf(float x) { return __float2bfloat16(x); }

__device__ __forceinline__ unsigned short f2bf_bits(float x) {
  union { float f; unsigned u; } a; a.f = x;
  unsigned u = a.u;
  unsigned r = u + 0x7FFFu + ((u >> 16) & 1u);
  return (unsigned short)(r >> 16);
}

#define MFMA16(a, b, c) __builtin_amdgcn_mfma_f32_16x16x32_bf16((a), (b), (c), 0, 0, 0)
#define GLDS(gsrc, ldst) __builtin_amdgcn_global_load_lds( \
    (const __attribute__((address_space(1))) void*)(gsrc), \
    (__attribute__((address_space(3))) void*)(ldst), 16, 0, 0)

// swizzled LDS address for a 16B chunk: rows of 64 bf16 (128B = 8 chunks),
// chunk slot XORed with row&7 so column-slice b128 reads spread across banks
__device__ __forceinline__ int swz(int row, int ch) {
  return row * 64 + ((ch ^ (row & 7)) * 8);
}

// ---------------- conversions ----------------
struct CvtArgs { const float* src[3]; bf16* dst[3]; int n4[3]; };

__global__ void cvt_kernel(CvtArgs a) {
  const int z = blockIdx.z;
  const float4* s = (const float4*)a.src[z];
  const int n4 = a.n4[z];
  const int i = blockIdx.x * blockDim.x + threadIdx.x;
  if (i < n4) {
    float4 v = s[i];
    ushort4 o;
    o.x = f2bf_bits(v.x); o.y = f2bf_bits(v.y);
    o.z = f2bf_bits(v.z); o.w = f2bf_bits(v.w);
    ((ushort4*)a.dst[z])[i] = o;
  }
}

// ---------------- weight transpose (f32 -> bf16, Wt[n][k] = W[k][n]) -------
struct TpArgs { const float* w[5]; bf16* o[5]; };

__global__ void tp_kernel(TpArgs a) {
  __shared__ float t[32][33];
  const int z = blockIdx.z;
  const float* W = a.w[z];
  bf16* Wt = a.o[z];
  const int bx = blockIdx.x * 32, by = blockIdx.y * 32;
  const int tx = threadIdx.x, ty = threadIdx.y;
#pragma unroll
  for (int y = ty; y < 32; y += 8) t[y][tx] = W[(long)(by + y) * D_ + bx + tx];
  __syncthreads();
#pragma unroll
  for (int y = ty; y < 32; y += 8)
    Wt[(long)(bx + y) * D_ + by + tx] = f2bf(t[tx][y]);
}

// ---------------- GEMM (A row-major MxK bf16, Bt row-major NxK bf16) -------
enum { EPI_HQKV = 0, EPI_MEMKV, EPI_R, EPI_OUT };

struct GemmArgs {
  const bf16* A; const bf16* Bt;
  int K;
  long batchA, batchB;
  bf16 *qw, *qr, *kall, *vT, *rhead;
  float *kcache, *vcache, *fout;
  const float *rwb, *rrb;
};

template <int MODE>
__global__ __launch_bounds__(256) void gemm_bt(GemmArgs g) {
  __shared__ bf16 As[128 * 32];
  __shared__ bf16 Bs[128 * 32];
  const int tid = threadIdx.x;
  const int wid = tid >> 6, lane = tid & 63;
  const int wr = wid >> 1, wc = wid & 1;
  const int lo = lane & 15, lg = lane >> 4;
  const int m0 = blockIdx.y * 128, n0 = blockIdx.x * 128;
  const int K = g.K;
  const bf16* A = g.A + (long)blockIdx.z * g.batchA;
  const bf16* Bt = g.Bt + (long)blockIdx.z * g.batchB;

  f32x4 acc[4][4] = {};

  const int srow = 32 * wid + (lane >> 2);
  const int scol = (lane & 3) * 8;
  const bf16* asrc = A + (long)(m0 + srow) * K + scol;
  const bf16* bsrc = Bt + (long)(n0 + srow) * K + scol;
  bf16* adst0 = &As[(32 * wid) * 32];
  bf16* adst1 = &As[(32 * wid + 16) * 32];
  bf16* bdst0 = &Bs[(32 * wid) * 32];
  bf16* bdst1 = &Bs[(32 * wid + 16) * 32];

  for (int kt = 0; kt < K; kt += 32) {
    GLDS(asrc, adst0);
    GLDS(asrc + 16 * (long)K, adst1);
    GLDS(bsrc, bdst0);
    GLDS(bsrc + 16 * (long)K, bdst1);
    asrc += 32; bsrc += 32;
    __syncthreads();
    bf16x8 af[4], bfv[4];
#pragma unroll
    for (int m = 0; m < 4; ++m)
      af[m] = *(const bf16x8*)&As[(64 * wr + 16 * m + lo) * 32 + lg * 8];
#pragma unroll
    for (int n = 0; n < 4; ++n)
      bfv[n] = *(const bf16x8*)&Bs[(64 * wc + 16 * n + lo) * 32 + lg * 8];
#pragma unroll
    for (int m = 0; m < 4; ++m)
#pragma unroll
      for (int n = 0; n < 4; ++n)
        acc[m][n] = MFMA16(af[m], bfv[n], acc[m][n]);
    __syncthreads();
  }

#pragma unroll
  for (int m = 0; m < 4; ++m) {
#pragma unroll
    for (int n = 0; n < 4; ++n) {
#pragma unroll
      for (int r = 0; r < 4; ++r) {
        const float v = acc[m][n][r];
        const int gr = m0 + 64 * wr + 16 * m + lg * 4 + r;
        const int gc = n0 + 64 * wc + 16 * n + lo;
        if constexpr (MODE == EPI_HQKV) {
          const int b = gr >> 10, i = gr & 1023;
          const int seg = gc >> 10, c = gc & 1023;
          const int hh = c >> 6, dh = c & 63;
          const long bh = (long)(b * H_ + hh);
          if (seg == 0) {
            // fold 1/sqrt(DH)=0.125 into q so attn skips the per-score scale
            const long idx = (bh * Q_ + i) * DH_ + dh;
            g.qw[idx] = f2bf((v + g.rwb[c]) * 0.125f);
            g.qr[idx] = f2bf((v + g.rrb[c]) * 0.125f);
          } else if (seg == 1) {
            g.kall[(bh * KLEN_ + MEM_ + i) * DH_ + dh] = f2bf(v);
            g.kcache[(bh * MEM_ + i) * DH_ + dh] = v;
          } else {
            g.vT[(bh * DH_ + dh) * KLEN_ + MEM_ + i] = f2bf(v);
            g.vcache[(bh * MEM_ + i) * DH_ + dh] = v;
          }
        } else if constexpr (MODE == EPI_MEMKV) {
          const int b = gr >> 10, i = gr & 1023;
          const int seg = gc >> 10, c = gc & 1023;
          const int hh = c >> 6, dh = c & 63;
          const long bh = (long)(b * H_ + hh);
          if (seg == 0) g.kall[(bh * KLEN_ + i) * DH_ + dh] = f2bf(v);
          else          g.vT[(bh * DH_ + dh) * KLEN_ + i] = f2bf(v);
        } else if constexpr (MODE == EPI_R) {
          const int hh = gc >> 6, dh = gc & 63;
          g.rhead[((long)hh * KLEN_ + gr) * DH_ + dh] = f2bf(v);
        } else {  // EPI_OUT
          g.fout[(long)gr * D_ + gc] = v;
        }
      }
    }
  }
}

// ---------------- fused attention, LDS-staged shared K/V/rhead -------------
// 1D grid of 2048 hw blocks; L = ((hw&7)<<8)|(hw>>3) keeps the 16 x-blocks of
// one (b,h,js) on one XCD. Per j-iter: ALL K/V/rhead-band data staged ONCE
// into LDS via global_load_lds (chunk-XOR-swizzled source, same XOR on read)
// and shared by the 4 waves -- kills the 4x redundant global loads that made
// R1-R5 latency-bound regardless of occupancy.
__global__ __launch_bounds__(256) void attn_kernel(
    const bf16* __restrict__ qw, const bf16* __restrict__ qr,
    const bf16* __restrict__ kall, const bf16* __restrict__ vT,
    const bf16* __restrict__ rhead, float* __restrict__ po,
    float2* __restrict__ pml) {
  __shared__ bf16 Kt[64 * 64];
  __shared__ bf16 Vt[64 * 64];
  __shared__ bf16 Rt[128 * 64];
  __shared__ bf16 Ps[4][16][72];
  __shared__ bf16 Sd[4][16][83];
  const int hw = blockIdx.x;
  const int L = ((hw & 7) << 8) | (hw >> 3);
  const int xb = L & 15;
  const int h = (L >> 4) & 15;
  const int js = (L >> 8) & 1;
  const int b = L >> 9;
  const int tid = threadIdx.x;
  const int wid = tid >> 6, lane = tid & 63;
  const int lo = lane & 15, lg = lane >> 4;
  const int I0 = xb * 64;
  const int i0 = I0 + wid * 16;
  const long bh = (long)(b * H_ + h);
  const bf16* rh = rhead + (long)h * KLEN_ * DH_;
  const bf16* kbase = kall + bh * KLEN_ * DH_;
  const bf16* vbase = vT + bh * DH_ * KLEN_;

  const bf16x8 aq0 = *(const bf16x8*)&qw[(bh * Q_ + i0 + lo) * DH_ + lg * 8];
  const bf16x8 aq1 = *(const bf16x8*)&qw[(bh * Q_ + i0 + lo) * DH_ + 32 + lg * 8];
  const bf16x8 ar0 = *(const bf16x8*)&qr[(bh * Q_ + i0 + lo) * DH_ + lg * 8];
  const bf16x8 ar1 = *(const bf16x8*)&qr[(bh * Q_ + i0 + lo) * DH_ + 32 + lg * 8];

  f32x4 o[4] = {};
  float mrun[4], lrun[4];
#pragma unroll
  for (int r = 0; r < 4; ++r) { mrun[r] = -1e30f; lrun[r] = 0.f; }

  const int jbeg = js << 10, jend = jbeg + (KLEN_ / NSPLIT);
  for (int j0 = jbeg; j0 < jend; j0 += 64) {
    // ---- STAGE: K (2 chunks/thread), V (2), rhead band (4) ----
    const int d0 = j0 - I0 - 63;  // lowest delta staged; Rt[c] = rhead[m(d0+c)]
#pragma unroll
    for (int s = 0; s < 2; ++s) {
      const int c = tid + s * 256;
      const int row = c >> 3;
      const int gch = (c & 7) ^ (row & 7);
      GLDS(kbase + (long)(j0 + row) * DH_ + gch * 8, &Kt[c * 8]);
    }
#pragma unroll
    for (int s = 0; s < 2; ++s) {
      const int c = tid + s * 256;
      const int row = c >> 3;
      const int gch = (c & 7) ^ (row & 7);
      GLDS(vbase + (long)row * KLEN_ + j0 + gch * 8, &Vt[c * 8]);
    }
#pragma unroll
    for (int s = 0; s < 4; ++s) {
      const int c = tid + s * 256;
      const int row = c >> 3;
      const int dcol = d0 + row;
      int m = dcol + ((dcol >= 1026) ? -1026 : 1023);
      m = max(0, min(m, KLEN_ - 1));
      const int gch = (c & 7) ^ (row & 7);
      GLDS(rh + (long)m * DH_ + gch * 8, &Rt[c * 8]);
    }
    __syncthreads();  // drains vmcnt: staged tiles visible to all waves

    // ---- ac = qw . K^T (from LDS) ----
    f32x4 s[4];
#pragma unroll
    for (int t = 0; t < 4; ++t) {
      const bf16x8 kb0 = *(const bf16x8*)&Kt[swz(16 * t + lo, lg)];
      const bf16x8 kb1 = *(const bf16x8*)&Kt[swz(16 * t + lo, lg + 4)];
      f32x4 z = {};
      z = MFMA16(aq0, kb0, z);
      z = MFMA16(aq1, kb1, z);
      s[t] = z;
    }
    // ---- bd band in delta-space (from staged Rt) ----
    const int dbase = j0 - i0 - 15;
#pragma unroll
    for (int t = 0; t < 5; ++t) {
      const int dmin = dbase + 16 * t;
      const bool need1 = (dmin <= 1024);
      const bool need2 = (dmin + 15 >= 1026);
      const int dcol = dmin + lo;
      const int c = 48 - 16 * wid + 16 * t + lo;  // Rt row for this lane
      const bf16x8 rb0 = *(const bf16x8*)&Rt[swz(c, lg)];
      const bf16x8 rb1 = *(const bf16x8*)&Rt[swz(c, lg + 4)];
      f32x4 z1 = {}, z2 = {};
      if (need1) { z1 = MFMA16(ar0, rb0, z1); z1 = MFMA16(ar1, rb1, z1); }
      if (need2) {
        const int rs = min(i0 + 1 + lo, Q_ - 1);
        const bf16x8 as0 = *(const bf16x8*)&qr[(bh * Q_ + rs) * DH_ + lg * 8];
        const bf16x8 as1 = *(const bf16x8*)&qr[(bh * Q_ + rs) * DH_ + 32 + lg * 8];
        z2 = MFMA16(as0, rb0, z2);
        z2 = MFMA16(as1, rb1, z2);
      }
#pragma unroll
      for (int r = 0; r < 4; ++r) {
        float v = (dcol >= 1026) ? z2[r] : z1[r];
        if (dcol == 1025) v = 0.f;
        Sd[wid][lg * 4 + r][16 * t + lo] = f2bf(v);
      }
    }
    // ---- softmax (online); q pre-scaled by 0.125 ----
    float mnew[4];
#pragma unroll
    for (int r = 0; r < 4; ++r) {
      const int row = lg * 4 + r;
      float mt = -1e30f;
#pragma unroll
      for (int t = 0; t < 4; ++t) {
        const float bd = bf2f(Sd[wid][row][16 * t + lo + 15 - row]);
        const float sc = s[t][r] + bd;
        s[t][r] = sc;
        mt = fmaxf(mt, sc);
      }
#pragma unroll
      for (int d = 1; d < 16; d <<= 1) mt = fmaxf(mt, __shfl_xor(mt, d));
      mnew[r] = fmaxf(mrun[r], mt);
    }
#pragma unroll
    for (int r = 0; r < 4; ++r) {
      float rsum = 0.f;
#pragma unroll
      for (int t = 0; t < 4; ++t) {
        const float p = __expf(s[t][r] - mnew[r]);
        s[t][r] = p;
        rsum += p;
      }
#pragma unroll
      for (int d = 1; d < 16; d <<= 1) rsum += __shfl_xor(rsum, d);
      const float scale = __expf(mrun[r] - mnew[r]);
      lrun[r] = lrun[r] * scale + rsum;
      mrun[r] = mnew[r];
#pragma unroll
      for (int u = 0; u < 4; ++u) o[u][r] *= scale;
    }
    // ---- P -> LDS -> A-frag, PV (V from LDS) ----
#pragma unroll
    for (int t = 0; t < 4; ++t)
#pragma unroll
      for (int r = 0; r < 4; ++r)
        Ps[wid][lg * 4 + r][16 * t + lo] = f2bf(s[t][r]);
    const bf16x8 pa0 = *(const bf16x8*)&Ps[wid][lo][lg * 8];
    const bf16x8 pa1 = *(const bf16x8*)&Ps[wid][lo][32 + lg * 8];
#pragma unroll
    for (int u = 0; u < 4; ++u) {
      const bf16x8 vb0 = *(const bf16x8*)&Vt[swz(16 * u + lo, lg)];
      const bf16x8 vb1 = *(const bf16x8*)&Vt[swz(16 * u + lo, lg + 4)];
      o[u] = MFMA16(pa0, vb0, o[u]);
      o[u] = MFMA16(pa1, vb1, o[u]);
    }
    __syncthreads();  // protect Kt/Vt/Rt before next stage overwrites
  }
  // ---- partial outputs ----
#pragma unroll
  for (int u = 0; u < 4; ++u) {
#pragma unroll
    for (int r = 0; r < 4; ++r) {
      const int i = i0 + lg * 4 + r;
      po[(((long)(bh * Q_ + i)) * NSPLIT + js) * DH_ + 16 * u + lo] = o[u][r];
    }
  }
  if (lo == 0) {
#pragma unroll
    for (int r = 0; r < 4; ++r) {
      const int i = i0 + lg * 4 + r;
      pml[((long)(bh * Q_ + i)) * NSPLIT + js] = make_float2(mrun[r], lrun[r]);
    }
  }
}

// ---------------- combine partial softmax halves ---------------------------
__global__ __launch_bounds__(256) void combine_kernel(
    const float* __restrict__ po, const float2* __restrict__ pml,
    bf16* __restrict__ attnv) {
  const long gid = (long)blockIdx.x * 256 + threadIdx.x;  // B*H*Q*DH
  const int col = gid & 63;
  const long row = gid >> 6;  // bh*Q + i
  const float2 ml0 = pml[row * NSPLIT];
  const float2 ml1 = pml[row * NSPLIT + 1];
  const float m = fmaxf(ml0.x, ml1.x);
  const float w0 = __expf(ml0.x - m), w1 = __expf(ml1.x - m);
  const float num = po[(row * NSPLIT) * DH_ + col] * w0 +
                    po[(row * NSPLIT + 1) * DH_ + col] * w1;
  const float den = ml0.y * w0 + ml1.y * w1;
  const int b = (int)(row >> 14);
  const int h = (int)(row >> 10) & 15;
  const int i = (int)row & 1023;
  attnv[((long)(b * Q_ + i)) * D_ + h * DH_ + col] = f2bf(num / den);
}

// ---------------- host ----------------
extern "C" void kernel_launch(void* const* d_in, const int* in_sizes, int n_in,
                              void* d_out, int out_size, void* d_ws, size_t ws_size,
                              hipStream_t stream) {
  (void)in_sizes; (void)n_in; (void)out_size; (void)ws_size;
  const float* h_in  = (const float*)d_in[0];
  const float* mem_in= (const float*)d_in[1];
  const float* r_in  = (const float*)d_in[2];
  const float* Wq = (const float*)d_in[3];
  const float* Wk = (const float*)d_in[4];
  const float* Wv = (const float*)d_in[5];
  const float* Wr = (const float*)d_in[6];
  const float* Wo = (const float*)d_in[7];
  const float* rwb = (const float*)d_in[8];
  const float* rrb = (const float*)d_in[9];

  float* out = (float*)d_out;
  float* kcache = out + (long)B_ * Q_ * D_;
  float* vcache = kcache + (long)B_ * H_ * MEM_ * DH_;

  char* w = (char*)d_ws;
  auto alloc = [&](size_t bytes) {
    char* p = w;
    w += (bytes + 255) & ~(size_t)255;
    return p;
  };
  bf16* h_bf   = (bf16*)alloc((size_t)B_ * Q_ * D_ * 2);
  bf16* mem_bf = (bf16*)alloc((size_t)B_ * MEM_ * D_ * 2);
  bf16* r_bf   = (bf16*)alloc((size_t)KLEN_ * D_ * 2);
  bf16* Wqt = (bf16*)alloc((size_t)D_ * D_ * 2);
  bf16* Wkt = (bf16*)alloc((size_t)D_ * D_ * 2);
  bf16* Wvt = (bf16*)alloc((size_t)D_ * D_ * 2);
  bf16* Wrt = (bf16*)alloc((size_t)D_ * D_ * 2);
  bf16* Wot = (bf16*)alloc((size_t)D_ * D_ * 2);
  bf16* qw    = (bf16*)alloc((size_t)B_ * H_ * Q_ * DH_ * 2);
  bf16* qr    = (bf16*)alloc((size_t)B_ * H_ * Q_ * DH_ * 2);
  bf16* kall  = (bf16*)alloc((size_t)B_ * H_ * KLEN_ * DH_ * 2);
  bf16* vT    = (bf16*)alloc((size_t)B_ * H_ * KLEN_ * DH_ * 2);
  bf16* rhead = (bf16*)alloc((size_t)H_ * KLEN_ * DH_ * 2);
  bf16* attnv = (bf16*)alloc((size_t)B_ * Q_ * D_ * 2);
  float* po   = (float*)alloc((size_t)B_ * H_ * Q_ * NSPLIT * DH_ * 4);
  float2* pml = (float2*)alloc((size_t)B_ * H_ * Q_ * NSPLIT * 8);

  // 1. f32 -> bf16 conversions
  CvtArgs ca;
  ca.src[0] = h_in;   ca.dst[0] = h_bf;   ca.n4[0] = B_ * Q_ * D_ / 4;
  ca.src[1] = mem_in; ca.dst[1] = mem_bf; ca.n4[1] = B_ * MEM_ * D_ / 4;
  ca.src[2] = r_in;   ca.dst[2] = r_bf;   ca.n4[2] = KLEN_ * D_ / 4;
  cvt_kernel<<<dim3((B_ * Q_ * D_ / 4 + 255) / 256, 1, 3), 256, 0, stream>>>(ca);

  // 2. weight transposes
  TpArgs ta;
  ta.w[0] = Wq; ta.o[0] = Wqt;
  ta.w[1] = Wk; ta.o[1] = Wkt;
  ta.w[2] = Wv; ta.o[2] = Wvt;
  ta.w[3] = Wr; ta.o[3] = Wrt;
  ta.w[4] = Wo; ta.o[4] = Wot;
  tp_kernel<<<dim3(32, 32, 5), dim3(32, 8), 0, stream>>>(ta);

  GemmArgs g{};
  g.qw = qw; g.qr = qr; g.kall = kall; g.vT = vT; g.rhead = rhead;
  g.kcache = kcache; g.vcache = vcache; g.fout = out; g.rwb = rwb; g.rrb = rrb;

  // 3. h @ [Wq|Wk|Wv]  (M=4096, N=3072, K=1024)
  g.A = h_bf; g.Bt = Wqt; g.K = D_; g.batchA = 0; g.batchB = 0;
  gemm_bt<EPI_HQKV><<<dim3(3 * D_ / 128, B_ * Q_ / 128, 1), 256, 0, stream>>>(g);

  // 4. mem @ [Wk|Wv]  (M=4096, N=2048, K=1024)
  g.A = mem_bf; g.Bt = Wkt;
  gemm_bt<EPI_MEMKV><<<dim3(2 * D_ / 128, B_ * MEM_ / 128, 1), 256, 0, stream>>>(g);

  // 5. r @ Wr  (M=2048, N=1024, K=1024)
  g.A = r_bf; g.Bt = Wrt;
  gemm_bt<EPI_R><<<dim3(D_ / 128, KLEN_ / 128, 1), 256, 0, stream>>>(g);

  // 6. fused attention (KV-split, XCD-swizzled, LDS-staged) + combine
  attn_kernel<<<dim3(Q_ / 64 * H_ * B_ * NSPLIT), 256, 0, stream>>>(
      qw, qr, kall, vT, rhead, po, pml);
  combine_kernel<<<dim3(B_ * H_ * Q_ * DH_ / 256), 256, 0, stream>>>(po, pml, attnv);

  // 7. out = attnv @ Wo  (M=4096, N=1024, K=1024)
  g.A = attnv; g.Bt = Wot; g.K = D_; g.batchA = 0; g.batchB = 0;
  gemm_bt<EPI_OUT><<<dim3(D_ / 128, B_ * Q_ / 128, 1), 256, 0, stream>>>(g);
}